// Round 6
// baseline (820.813 us; speedup 1.0000x reference)
//
#include <hip/hip_runtime.h>
#include <hip/hip_bf16.h>
#include <stdint.h>

#define M_DIM 8192
#define N_DIM 11008
#define K_DIM 4096

typedef __attribute__((ext_vector_type(8))) short bf16x8;
typedef __attribute__((ext_vector_type(4))) float f32x4;
typedef __attribute__((ext_vector_type(16))) float f32x16;

// ---------------- FP4 code table (bitsandbytes), fp32-exact ----------------
__device__ const float kCodes[16] = {
    -1.0f, -(float)(2.0 / 3.0), -0.5f, -(float)(1.0 / 3.0), -0.25f,
    -(float)(1.0 / 6.0), -0.0052083333f, -0.0f,
    0.0f, 0.0052083333f, (float)(1.0 / 6.0), 0.25f,
    (float)(1.0 / 3.0), 0.5f, (float)(2.0 / 3.0), 1.0f};

__device__ __forceinline__ float fp4_bound(int i) {
  return (kCodes[i] + kCodes[i + 1]) * 0.5f;
}

__device__ __forceinline__ unsigned short f2bf(float f) {
  uint32_t u = __float_as_uint(f);
  u = (u + 0x7FFFu + ((u >> 16) & 1u)) >> 16;
  return (unsigned short)u;
}

__device__ __forceinline__ float fp4_rt(float w, float d, float am) {
  float n = w / d;
  int idx = 0;
#pragma unroll
  for (int i = 0; i < 15; ++i) idx += (n > fp4_bound(i)) ? 1 : 0;
  return kCodes[idx] * am;
}

// ---------------- Kernel 1: quantize->dequantize weight to bf16 ----------------
__global__ void quant_fp4_kernel(const float* __restrict__ W,
                                 unsigned short* __restrict__ Wq) {
  int t = blockIdx.x * 256 + threadIdx.x;
  size_t base = (size_t)t * 4;
  float4 v = *reinterpret_cast<const float4*>(W + base);
  float am = fmaxf(fmaxf(fabsf(v.x), fabsf(v.y)), fmaxf(fabsf(v.z), fabsf(v.w)));
  am = fmaxf(am, __shfl_xor(am, 1));
  am = fmaxf(am, __shfl_xor(am, 2));
  am = fmaxf(am, __shfl_xor(am, 4));
  am = fmaxf(am, __shfl_xor(am, 8));
  float d = fmaxf(am, 1e-12f);
  ushort4 o;
  o.x = f2bf(fp4_rt(v.x, d, am));
  o.y = f2bf(fp4_rt(v.y, d, am));
  o.z = f2bf(fp4_rt(v.z, d, am));
  o.w = f2bf(fp4_rt(v.w, d, am));
  *reinterpret_cast<ushort4*>(Wq + base) = o;
}

// ---------------- Kernel 2: cast x fp32 -> bf16 ----------------
__device__ __forceinline__ uint32_t pack2(float lo, float hi) {
  return (uint32_t)f2bf(lo) | ((uint32_t)f2bf(hi) << 16);
}

__global__ void cast_bf16_kernel(const float* __restrict__ X,
                                 uint32_t* __restrict__ Y) {
  int t = blockIdx.x * 256 + threadIdx.x;
  size_t base = (size_t)t * 8;
  float4 a = *reinterpret_cast<const float4*>(X + base);
  float4 b = *reinterpret_cast<const float4*>(X + base + 4);
  uint4 o;
  o.x = pack2(a.x, a.y);
  o.y = pack2(a.z, a.w);
  o.z = pack2(b.x, b.y);
  o.w = pack2(b.z, b.w);
  *reinterpret_cast<uint4*>(Y + (size_t)t * 4) = o;
}

// ---------------- Kernel 3: 256x256 8-phase PIPELINED bf16 GEMM, 32x32x16 ---
// C[M,N] = A[M,K] * B[N,K]^T + bias.  BM=BN=256, BK=64, 512 thr = 8 waves
// (2M x 4N), per-wave out 128x64 = 4x2 tiles of 32x32, acc[4][2] f32x16.
// LDS 128KB: [2 dbuf][A0,A1,B0,B1][16KB half], 3-bit XOR swizzle
// (phys = row*128 + (colbyte ^ ((row&7)<<4))), zero bank conflicts (r4-proven;
// 32-row fragment reads re-verified per quarter-wave: slot = 2kk^(l&7) -> 2
// lanes/slot).  Register-pipelined: phase p issues ds_reads for p+1 (ping-pong
// afA/afB; kk-fixed B-pairs P0..P3), counted lgkm waits, 1 barrier/phase,
// vmcnt(0) only at buffer handoff (ph2/ph6).  Staging slots provably safe:
// B(next)@ph0/ph4, A(next)@ph1/ph5, each >= last-read-complete + barrier.
#define GLOAD(src, dst)                                                        \
  __builtin_amdgcn_global_load_lds(                                           \
      (const __attribute__((address_space(1))) void*)(src),                   \
      (__attribute__((address_space(3))) void*)(dst), 16, 0, 0)

#define WAIT_LGKM(N)                                                           \
  asm volatile("s_waitcnt lgkmcnt(" #N ")" ::: "memory");                      \
  __builtin_amdgcn_sched_barrier(0);                                           \
  __builtin_amdgcn_s_setprio(1);

#define ENDBAR()                                                               \
  __builtin_amdgcn_s_setprio(0);                                               \
  __builtin_amdgcn_sched_barrier(0);                                           \
  __builtin_amdgcn_s_barrier();

#define ENDBAR_VM0()                                                           \
  __builtin_amdgcn_s_setprio(0);                                               \
  __builtin_amdgcn_sched_barrier(0);                                           \
  asm volatile("s_waitcnt vmcnt(0)" ::: "memory");                             \
  __builtin_amdgcn_s_barrier();

#define RD_A(dst, base, ok)                                                    \
  _Pragma("unroll") for (int m = 0; m < 4; ++m) dst[m] =                       \
      *(const bf16x8*)((base) + m * 4096 + (ok));

#define RD_B(dst, base, ok)                                                    \
  _Pragma("unroll") for (int n = 0; n < 2; ++n) dst[n] =                       \
      *(const bf16x8*)((base) + n * 4096 + (ok));

#define MFMA8(AF, BP)                                                          \
  _Pragma("unroll") for (int m = 0; m < 4; ++m) {                              \
    acc[m][0] = __builtin_amdgcn_mfma_f32_32x32x16_bf16(AF[m], BP[0],          \
                                                        acc[m][0], 0, 0, 0);   \
    acc[m][1] = __builtin_amdgcn_mfma_f32_32x32x16_bf16(AF[m], BP[1],          \
                                                        acc[m][1], 0, 0, 0);   \
  }

__global__ __launch_bounds__(512, 2) void gemm256_kernel(
    const short* __restrict__ A, const short* __restrict__ B,
    const float* __restrict__ bias, float* __restrict__ C) {
  __shared__ short lds[2][4][8192];  // [buf][A0,A1,B0,B1][16KB half]

  const int tid = threadIdx.x;
  const int wave = tid >> 6;
  const int lane = tid & 63;
  const int l31 = lane & 31;
  const int wm = wave >> 2;  // 0..1
  const int wn = wave & 3;   // 0..3

  // XCD-chunked swizzle: 1376 blocks = 8 XCDs x 172
  const int bid = blockIdx.x;
  const int g = bid & 7;
  const int idx = bid >> 3;  // 0..171
  const int brow = (g * 4 + (idx & 3)) * 256;
  const int bcol = (idx >> 2) * 256;

  // staging source (inverse-swizzled global addr; linear LDS dest)
  const int srow = tid >> 3;                             // 0..63
  const int scol = ((tid & 7) ^ ((tid >> 3) & 7)) << 3;  // element col
  const short* Asrc = A + (size_t)(brow + srow) * K_DIM + scol;
  const short* Bsrc = B + (size_t)(bcol + srow) * K_DIM + scol;
  const int wu0 = wave * 512;
  const int wu1 = 4096 + wave * 512;

  auto stageA = [&](int buf, int half, int t) {
    const short* s = Asrc + (size_t)half * 128 * K_DIM + t * 64;
    GLOAD(s, &lds[buf][half][wu0]);
    GLOAD(s + (size_t)64 * K_DIM, &lds[buf][half][wu1]);
  };
  auto stageB = [&](int buf, int half, int t) {
    const short* s = Bsrc + (size_t)half * 128 * K_DIM + t * 64;
    GLOAD(s, &lds[buf][2 + half][wu0]);
    GLOAD(s + (size_t)64 * K_DIM, &lds[buf][2 + half][wu1]);
  };

  // 32x32x16 fragment read offsets (swizzle folded): lane reads 16B at
  //   row = tile_row*32 + (l&31); logical kbyte = kk*32 + (l>>5)*16
  //   phys  = kbyte ^ ((l&7)<<4)   [row&7 == l&7 since tile rows % 32 == 0]
  const int swz = (lane & 7) << 4;
  const int ok0 = (((lane >> 5) << 4) | 0x00) ^ swz;
  const int ok1 = (((lane >> 5) << 4) | 0x20) ^ swz;
  const int ok2 = (((lane >> 5) << 4) | 0x40) ^ swz;
  const int ok3 = (((lane >> 5) << 4) | 0x60) ^ swz;

  const char* aP[2] = {(const char*)&lds[0][wm][0] + l31 * 128,
                       (const char*)&lds[1][wm][0] + l31 * 128};
  const char* bP[2] = {
      (const char*)&lds[0][2 + (wn >> 1)][0] + (wn & 1) * 8192 + l31 * 128,
      (const char*)&lds[1][2 + (wn >> 1)][0] + (wn & 1) * 8192 + l31 * 128};

  f32x16 acc[4][2] = {};
  bf16x8 afA[4], afB[4], P0[2], P1[2], P2[2], P3[2];

  // ---- prologue: stage buf0 (tile0, 8 gloads); read S0 ----
  stageB(0, 0, 0);
  stageB(0, 1, 0);
  stageA(0, 0, 0);
  stageA(0, 1, 0);
  asm volatile("s_waitcnt vmcnt(0)" ::: "memory");
  __builtin_amdgcn_s_barrier();
  RD_A(afA, aP[0], ok0);
  RD_B(P0, bP[0], ok0);
  RD_B(P1, bP[0], ok1);

  for (int i = 0; i < 32; ++i) {
    const int t1 = 2 * i + 1;
    const int t2 = (2 * i + 2 < 64) ? 2 * i + 2 : 63;  // clamped tail (dead)
    const int t3 = (2 * i + 3 < 64) ? 2 * i + 3 : 63;

    // ph0: rd afB<-b0A.k1; stage B(1,*,t1); MFMA k0
    RD_A(afB, aP[0], ok1);
    stageB(1, 0, t1);
    stageB(1, 1, t1);
    WAIT_LGKM(4);
    MFMA8(afA, P0);
    ENDBAR();

    // ph1: rd afA<-b0A.k2, P2<-b0B.k2; stage A(1,*,t1); MFMA k1
    RD_A(afA, aP[0], ok2);
    RD_B(P2, bP[0], ok2);
    stageA(1, 0, t1);
    stageA(1, 1, t1);
    WAIT_LGKM(6);
    MFMA8(afB, P1);
    ENDBAR();

    // ph2: rd afB<-b0A.k3, P3<-b0B.k3; MFMA k2; END: vmcnt(0) [buf1 landed]
    RD_A(afB, aP[0], ok3);
    RD_B(P3, bP[0], ok3);
    WAIT_LGKM(6);
    MFMA8(afA, P2);
    ENDBAR_VM0();

    // ph3: rd afA<-b1A.k0, P0<-b1B.k0, P1<-b1B.k1; MFMA k3
    RD_A(afA, aP[1], ok0);
    RD_B(P0, bP[1], ok0);
    RD_B(P1, bP[1], ok1);
    WAIT_LGKM(8);
    MFMA8(afB, P3);
    ENDBAR();

    // ph4: rd afB<-b1A.k1; stage B(0,*,t2); MFMA k0'
    RD_A(afB, aP[1], ok1);
    stageB(0, 0, t2);
    stageB(0, 1, t2);
    WAIT_LGKM(4);
    MFMA8(afA, P0);
    ENDBAR();

    // ph5: rd afA<-b1A.k2, P2<-b1B.k2; stage A(0,*,t2); MFMA k1'
    RD_A(afA, aP[1], ok2);
    RD_B(P2, bP[1], ok2);
    stageA(0, 0, t2);
    stageA(0, 1, t2);
    WAIT_LGKM(6);
    MFMA8(afB, P1);
    ENDBAR();

    // ph6: rd afB<-b1A.k3, P3<-b1B.k3; MFMA k2'; END: vmcnt(0) [buf0' landed]
    RD_A(afB, aP[1], ok3);
    RD_B(P3, bP[1], ok3);
    WAIT_LGKM(6);
    MFMA8(afA, P2);
    ENDBAR_VM0();

    // ph7: rd afA<-b0A.k0(next), P0/P1<-b0B.k0/k1(next); stage -; MFMA k3'
    RD_A(afA, aP[0], ok0);
    RD_B(P0, bP[0], ok0);
    RD_B(P1, bP[0], ok1);
    WAIT_LGKM(8);
    MFMA8(afB, P3);
    ENDBAR();
  }

  // ---- epilogue: 32x32 C/D: col=lane&31, row=(j&3)+8*(j>>2)+4*(lane>>5) ----
  const int crow0 = brow + wm * 128 + 4 * (lane >> 5);
  const int ccol0 = bcol + wn * 64 + l31;
#pragma unroll
  for (int n = 0; n < 2; ++n) {
    const float bv = bias[ccol0 + n * 32];
#pragma unroll
    for (int m = 0; m < 4; ++m) {
#pragma unroll
      for (int j = 0; j < 16; ++j) {
        const int row = crow0 + m * 32 + (j & 3) + 8 * (j >> 2);
        C[(size_t)row * N_DIM + ccol0 + n * 32] = acc[m][n][j] + bv;
      }
    }
  }
}

extern "C" void kernel_launch(void* const* d_in, const int* in_sizes, int n_in,
                              void* d_out, int out_size, void* d_ws, size_t ws_size,
                              hipStream_t stream) {
  const float* x = (const float*)d_in[0];     // [8192, 4096]
  const float* w = (const float*)d_in[1];     // [11008, 4096]
  const float* bias = (const float*)d_in[2];  // [11008]
  float* out = (float*)d_out;                 // [8192, 11008]

  unsigned short* wq = (unsigned short*)d_ws;       // N*K bf16
  unsigned short* xb = wq + (size_t)N_DIM * K_DIM;  // M*K bf16

  {
    int nt = N_DIM * K_DIM / 4;
    quant_fp4_kernel<<<nt / 256, 256, 0, stream>>>(w, wq);
  }
  {
    int nt = M_DIM * K_DIM / 8;
    cast_bf16_kernel<<<nt / 256, 256, 0, stream>>>(x, (uint32_t*)xb);
  }
  {
    // 1376 = (8192/256) * (11008/256) = 8 XCD-chunks x 172
    gemm256_kernel<<<dim3(1376), 512, 0, stream>>>((const short*)xb,
                                                   (const short*)wq, bias, out);
  }
}

// Round 7
// 770.423 us; speedup vs baseline: 1.0654x; 1.0654x over previous
//
#include <hip/hip_runtime.h>
#include <hip/hip_bf16.h>
#include <stdint.h>

#define M_DIM 8192
#define N_DIM 11008
#define K_DIM 4096
#define NTILE 128  // K_DIM / 32

typedef __attribute__((ext_vector_type(8))) short bf16x8;
typedef __attribute__((ext_vector_type(4))) float f32x4;

// ---------------- FP4 code table (bitsandbytes), fp32-exact ----------------
__device__ const float kCodes[16] = {
    -1.0f, -(float)(2.0 / 3.0), -0.5f, -(float)(1.0 / 3.0), -0.25f,
    -(float)(1.0 / 6.0), -0.0052083333f, -0.0f,
    0.0f, 0.0052083333f, (float)(1.0 / 6.0), 0.25f,
    (float)(1.0 / 3.0), 0.5f, (float)(2.0 / 3.0), 1.0f};

__device__ __forceinline__ float fp4_bound(int i) {
  return (kCodes[i] + kCodes[i + 1]) * 0.5f;
}

__device__ __forceinline__ unsigned short f2bf(float f) {
  uint32_t u = __float_as_uint(f);
  u = (u + 0x7FFFu + ((u >> 16) & 1u)) >> 16;
  return (unsigned short)u;
}

__device__ __forceinline__ float fp4_rt(float w, float d, float am) {
  float n = w / d;
  int idx = 0;
#pragma unroll
  for (int i = 0; i < 15; ++i) idx += (n > fp4_bound(i)) ? 1 : 0;
  return kCodes[idx] * am;
}

// ---------------- Kernel 1: quantize->dequantize weight to bf16 ----------------
__global__ void quant_fp4_kernel(const float* __restrict__ W,
                                 unsigned short* __restrict__ Wq) {
  int t = blockIdx.x * 256 + threadIdx.x;
  size_t base = (size_t)t * 4;
  float4 v = *reinterpret_cast<const float4*>(W + base);
  float am = fmaxf(fmaxf(fabsf(v.x), fabsf(v.y)), fmaxf(fabsf(v.z), fabsf(v.w)));
  am = fmaxf(am, __shfl_xor(am, 1));
  am = fmaxf(am, __shfl_xor(am, 2));
  am = fmaxf(am, __shfl_xor(am, 4));
  am = fmaxf(am, __shfl_xor(am, 8));
  float d = fmaxf(am, 1e-12f);
  ushort4 o;
  o.x = f2bf(fp4_rt(v.x, d, am));
  o.y = f2bf(fp4_rt(v.y, d, am));
  o.z = f2bf(fp4_rt(v.z, d, am));
  o.w = f2bf(fp4_rt(v.w, d, am));
  *reinterpret_cast<ushort4*>(Wq + base) = o;
}

// ---------------- Kernel 2: cast x fp32 -> bf16 ----------------
__device__ __forceinline__ uint32_t pack2(float lo, float hi) {
  return (uint32_t)f2bf(lo) | ((uint32_t)f2bf(hi) << 16);
}

__global__ void cast_bf16_kernel(const float* __restrict__ X,
                                 uint32_t* __restrict__ Y) {
  int t = blockIdx.x * 256 + threadIdx.x;
  size_t base = (size_t)t * 8;
  float4 a = *reinterpret_cast<const float4*>(X + base);
  float4 b = *reinterpret_cast<const float4*>(X + base + 4);
  uint4 o;
  o.x = pack2(a.x, a.y);
  o.y = pack2(a.z, a.w);
  o.z = pack2(b.x, b.y);
  o.w = pack2(b.z, b.w);
  *reinterpret_cast<uint4*>(Y + (size_t)t * 4) = o;
}

// ---------------- Kernel 3: 256x256 bf16 GEMM, 4-ring BK=32, counted vmcnt --
// C[M,N] = A[M,K]*B[N,K]^T + bias. 512 thr = 8 waves (2M x 4N), 16x16x32 MFMA,
// acc[8][4] f32x4/wave. LDS 128KB = 4 ring-bufs x (A 16KB + B 16KB), BK=32.
// 2 phases per K-tile (EVEN: m0-3, ODD: m4-7), 16 MFMA/wave each; ds_reads
// issued 1 phase ahead with counted lgkm; staging 3 K-tiles ahead; vmcnt(6)
// (never 0) at EVEN-end before the barrier that precedes next-buf reads.
// Hazards: stage into buf (t+3)&3 at tile t -- buf's old reads drained by
// ODD(t-1)'s lgkm(8) + barrier.  BK=32 rows are 64B: swizzle
//   phys = row*64 + (kbyte ^ (((row>>1)&3)<<4))
// -> per 16-lane group each (row-parity, 16B-slot) pair hit exactly 2x -> all
// 32 banks balanced. Staging keeps LDS dest linear, inverse-swizzles the
// global source (rule #21).
#define GLOAD(src, dst)                                                        \
  __builtin_amdgcn_global_load_lds(                                           \
      (const __attribute__((address_space(1))) void*)(src),                   \
      (__attribute__((address_space(3))) void*)(dst), 16, 0, 0)

#define WAIT_LGKM(N)                                                           \
  asm volatile("s_waitcnt lgkmcnt(" #N ")" ::: "memory");                      \
  __builtin_amdgcn_sched_barrier(0);                                           \
  __builtin_amdgcn_s_setprio(1);

#define ENDBAR()                                                               \
  __builtin_amdgcn_s_setprio(0);                                               \
  __builtin_amdgcn_sched_barrier(0);                                           \
  __builtin_amdgcn_s_barrier();

#define ENDBAR_VM6()                                                           \
  __builtin_amdgcn_s_setprio(0);                                               \
  __builtin_amdgcn_sched_barrier(0);                                           \
  asm volatile("s_waitcnt vmcnt(6)" ::: "memory");                             \
  __builtin_amdgcn_s_barrier();

// One K-tile t = 4*i+B. BN=(B+1)&3 (next buf), BS=(B+3)&3 (stage target).
// CUR = B-frags of tile t (read at prior ODD); NXT = B-frags of tile t+1.
#define TILE(B, BN, BS, CUR, NXT)                                              \
  {                                                                            \
    const int ts = ((4 * i + (B) + 3) < NTILE) ? (4 * i + (B) + 3) : NTILE - 1;\
    /* EVEN: read afB (m4-7 of buf B); stage A(ts)->BS; MFMA m0-3 */           \
    _Pragma("unroll") for (int m = 0; m < 4; ++m) afB[m] =                     \
        *(const bf16x8*)(aB[B] + (4 + m) * 1024 + okA);                        \
    stA(BS, ts);                                                               \
    WAIT_LGKM(4);                                                              \
    _Pragma("unroll") for (int m = 0; m < 4; ++m)                              \
      _Pragma("unroll") for (int n = 0; n < 4; ++n) acc[m][n] =                \
          __builtin_amdgcn_mfma_f32_16x16x32_bf16(afA[m], CUR[n], acc[m][n],   \
                                                  0, 0, 0);                    \
    ENDBAR_VM6();                                                              \
    /* ODD: read afA + NXT from buf BN; stage B(ts)->BS; MFMA m4-7 */          \
    _Pragma("unroll") for (int m = 0; m < 4; ++m) afA[m] =                     \
        *(const bf16x8*)(aB[BN] + m * 1024 + okA);                             \
    _Pragma("unroll") for (int n = 0; n < 4; ++n) NXT[n] =                     \
        *(const bf16x8*)(bB[BN] + n * 1024 + okA);                             \
    stB(BS, ts);                                                               \
    WAIT_LGKM(8);                                                              \
    _Pragma("unroll") for (int m = 0; m < 4; ++m)                              \
      _Pragma("unroll") for (int n = 0; n < 4; ++n) acc[4 + m][n] =            \
          __builtin_amdgcn_mfma_f32_16x16x32_bf16(afB[m], CUR[n],              \
                                                  acc[4 + m][n], 0, 0, 0);     \
    ENDBAR();                                                                  \
  }

__global__ __launch_bounds__(512, 2) void gemm256_kernel(
    const short* __restrict__ A, const short* __restrict__ B,
    const float* __restrict__ bias, float* __restrict__ C) {
  __shared__ short lds[4][2][8192];  // [ring buf][A|B][16KB: 256 rows x 64B]

  const int tid = threadIdx.x;
  const int wave = tid >> 6;
  const int lane = tid & 63;
  const int l15 = lane & 15;
  const int q4 = lane >> 4;
  const int wm = wave >> 2;  // 0..1
  const int wn = wave & 3;   // 0..3

  // XCD-chunked swizzle: 1376 blocks = 8 XCDs x 172
  const int bid = blockIdx.x;
  const int g = bid & 7;
  const int idx = bid >> 3;  // 0..171
  const int brow = (g * 4 + (idx & 3)) * 256;
  const int bcol = (idx >> 2) * 256;

  // staging source (inverse-swizzled global addr; linear LDS dest).
  // thread t writes phys bytes [t*16,t*16+16) of an 8KB chunk (128 rows):
  //   phys row = t>>2, phys slot = t&3 -> logical slot = (t&3)^((t>>3)&3)
  const int srow = tid >> 2;                             // 0..127
  const int scol = ((tid & 3) ^ ((tid >> 3) & 3)) << 3;  // element col
  const short* Asrc = A + (size_t)(brow + srow) * K_DIM + scol;
  const short* Bsrc = B + (size_t)(bcol + srow) * K_DIM + scol;
  const int wu = wave * 512;  // shorts: wave-uniform base (lane*16B appended)

  auto stA = [&](int buf, int t) {
    const short* s = Asrc + t * 32;
    GLOAD(s, &lds[buf][0][wu]);
    GLOAD(s + (size_t)128 * K_DIM, &lds[buf][0][wu + 4096]);
  };
  auto stB = [&](int buf, int t) {
    const short* s = Bsrc + t * 32;
    GLOAD(s, &lds[buf][1][wu]);
    GLOAD(s + (size_t)128 * K_DIM, &lds[buf][1][wu + 4096]);
  };

  // fragment read: frag row r, k-slot q4: phys = r*64 + ((q4^((r>>1)&3))<<4);
  // r = wm*128 + m*16 + l15 (A) or wn*64 + n*16 + l15 (B): (r>>1)&3 dep. l15 only
  const int okA = ((q4 ^ ((l15 >> 1) & 3)) << 4);
  const char* aB[4];
  const char* bB[4];
#pragma unroll
  for (int b = 0; b < 4; ++b) {
    aB[b] = (const char*)&lds[b][0][0] + (wm * 128 + l15) * 64;
    bB[b] = (const char*)&lds[b][1][0] + (wn * 64 + l15) * 64;
  }

  f32x4 acc[8][4] = {};
  bf16x8 afA[4], afB[4], bfA[4], bfB[4];

  // ---- prologue: stage tiles 0,1,2 (12 gloads); wait tile0; read S0 ----
  stA(0, 0);
  stB(0, 0);
  stA(1, 1);
  stB(1, 1);
  stA(2, 2);
  stB(2, 2);
  asm volatile("s_waitcnt vmcnt(8)" ::: "memory");  // tile0's 4 landed
  __builtin_amdgcn_s_barrier();
#pragma unroll
  for (int m = 0; m < 4; ++m) afA[m] = *(const bf16x8*)(aB[0] + m * 1024 + okA);
#pragma unroll
  for (int n = 0; n < 4; ++n) bfA[n] = *(const bf16x8*)(bB[0] + n * 1024 + okA);

  for (int i = 0; i < 32; ++i) {
    TILE(0, 1, 3, bfA, bfB);
    TILE(1, 2, 0, bfB, bfA);
    TILE(2, 3, 1, bfA, bfB);
    TILE(3, 0, 2, bfB, bfA);
  }

  // ---- epilogue: C/D layout col=lane&15, row=(lane>>4)*4+j ----
  const int crow0 = brow + wm * 128 + q4 * 4;
  const int ccol0 = bcol + wn * 64 + l15;
#pragma unroll
  for (int n = 0; n < 4; ++n) {
    const float bv = bias[ccol0 + n * 16];
#pragma unroll
    for (int m = 0; m < 8; ++m) {
      const size_t rb = (size_t)(crow0 + m * 16) * N_DIM + (ccol0 + n * 16);
#pragma unroll
      for (int j = 0; j < 4; ++j) C[rb + (size_t)j * N_DIM] = acc[m][n][j] + bv;
    }
  }
}

extern "C" void kernel_launch(void* const* d_in, const int* in_sizes, int n_in,
                              void* d_out, int out_size, void* d_ws, size_t ws_size,
                              hipStream_t stream) {
  const float* x = (const float*)d_in[0];     // [8192, 4096]
  const float* w = (const float*)d_in[1];     // [11008, 4096]
  const float* bias = (const float*)d_in[2];  // [11008]
  float* out = (float*)d_out;                 // [8192, 11008]

  unsigned short* wq = (unsigned short*)d_ws;       // N*K bf16
  unsigned short* xb = wq + (size_t)N_DIM * K_DIM;  // M*K bf16

  {
    int nt = N_DIM * K_DIM / 4;
    quant_fp4_kernel<<<nt / 256, 256, 0, stream>>>(w, wq);
  }
  {
    int nt = M_DIM * K_DIM / 8;
    cast_bf16_kernel<<<nt / 256, 256, 0, stream>>>(x, (uint32_t*)xb);
  }
  {
    // 1376 = (8192/256) * (11008/256) = 8 XCD-chunks x 172
    gemm256_kernel<<<dim3(1376), 512, 0, stream>>>((const short*)xb,
                                                   (const short*)wq, bias, out);
  }
}

// Round 8
// 761.903 us; speedup vs baseline: 1.0773x; 1.0112x over previous
//
#include <hip/hip_runtime.h>
#include <hip/hip_bf16.h>
#include <stdint.h>

#define M_DIM 8192
#define N_DIM 11008
#define K_DIM 4096
#define NQB 44032  // quant blocks: N*K/4/256
#define NCB 16384  // cast blocks:  M*K/8/256

typedef __attribute__((ext_vector_type(8))) short bf16x8;
typedef __attribute__((ext_vector_type(4))) float f32x4;

// ---------------- FP4 code table (bitsandbytes), fp32-exact ----------------
__device__ const float kCodes[16] = {
    -1.0f, -(float)(2.0 / 3.0), -0.5f, -(float)(1.0 / 3.0), -0.25f,
    -(float)(1.0 / 6.0), -0.0052083333f, -0.0f,
    0.0f, 0.0052083333f, (float)(1.0 / 6.0), 0.25f,
    (float)(1.0 / 3.0), 0.5f, (float)(2.0 / 3.0), 1.0f};

__device__ __forceinline__ float fp4_bound(int i) {
  return (kCodes[i] + kCodes[i + 1]) * 0.5f;
}

__device__ __forceinline__ unsigned short f2bf(float f) {
  uint32_t u = __float_as_uint(f);
  u = (u + 0x7FFFu + ((u >> 16) & 1u)) >> 16;
  return (unsigned short)u;
}

__device__ __forceinline__ float fp4_rt(float w, float d, float am) {
  float n = w / d;
  int idx = 0;
#pragma unroll
  for (int i = 0; i < 15; ++i) idx += (n > fp4_bound(i)) ? 1 : 0;
  return kCodes[idx] * am;
}

__device__ __forceinline__ uint32_t pack2(float lo, float hi) {
  return (uint32_t)f2bf(lo) | ((uint32_t)f2bf(hi) << 16);
}

// ---------------- Kernel 1: fused {W quant->dequant->bf16} + {x cast} -------
__global__ void prep_kernel(const float* __restrict__ W,
                            unsigned short* __restrict__ Wq,
                            const float* __restrict__ X,
                            uint32_t* __restrict__ Y) {
  const int bid = blockIdx.x;
  if (bid < NQB) {
    // quantize->dequantize weight: 4 elems/thread, 16 lanes = one 64-block
    int t = bid * 256 + threadIdx.x;
    size_t base = (size_t)t * 4;
    float4 v = *reinterpret_cast<const float4*>(W + base);
    float am =
        fmaxf(fmaxf(fabsf(v.x), fabsf(v.y)), fmaxf(fabsf(v.z), fabsf(v.w)));
    am = fmaxf(am, __shfl_xor(am, 1));
    am = fmaxf(am, __shfl_xor(am, 2));
    am = fmaxf(am, __shfl_xor(am, 4));
    am = fmaxf(am, __shfl_xor(am, 8));
    float d = fmaxf(am, 1e-12f);
    ushort4 o;
    o.x = f2bf(fp4_rt(v.x, d, am));
    o.y = f2bf(fp4_rt(v.y, d, am));
    o.z = f2bf(fp4_rt(v.z, d, am));
    o.w = f2bf(fp4_rt(v.w, d, am));
    *reinterpret_cast<ushort4*>(Wq + base) = o;
  } else {
    // cast x fp32 -> bf16, 8 elems/thread
    int t = (bid - NQB) * 256 + threadIdx.x;
    size_t base = (size_t)t * 8;
    float4 a = *reinterpret_cast<const float4*>(X + base);
    float4 b = *reinterpret_cast<const float4*>(X + base + 4);
    uint4 o;
    o.x = pack2(a.x, a.y);
    o.y = pack2(a.z, a.w);
    o.z = pack2(b.x, b.y);
    o.w = pack2(b.z, b.w);
    *reinterpret_cast<uint4*>(Y + (size_t)t * 4) = o;
  }
}

// ---------------- Kernel 2: 256x256 8-phase PIPELINED bf16 GEMM (R5) --------
// Handles N-cols 0..10239 (40 tile-cols): 1280 blocks = exactly 5 rounds at
// 1 block/CU -> zero grid tail. Structure identical to round-5 kernel
// (best measured: 667us, MfmaUtil 52, 0 bank conflicts).
#define GLOAD(src, dst)                                                        \
  __builtin_amdgcn_global_load_lds(                                           \
      (const __attribute__((address_space(1))) void*)(src),                   \
      (__attribute__((address_space(3))) void*)(dst), 16, 0, 0)

#define WAIT_LGKM(N)                                                           \
  asm volatile("s_waitcnt lgkmcnt(" #N ")" ::: "memory");                      \
  __builtin_amdgcn_sched_barrier(0);                                           \
  __builtin_amdgcn_s_setprio(1);

#define ENDBAR()                                                               \
  __builtin_amdgcn_s_setprio(0);                                               \
  __builtin_amdgcn_sched_barrier(0);                                           \
  __builtin_amdgcn_s_barrier();

#define ENDBAR_VM0()                                                           \
  __builtin_amdgcn_s_setprio(0);                                               \
  __builtin_amdgcn_sched_barrier(0);                                           \
  asm volatile("s_waitcnt vmcnt(0)" ::: "memory");                             \
  __builtin_amdgcn_s_barrier();

__global__ __launch_bounds__(512, 2) void gemm256_kernel(
    const short* __restrict__ A, const short* __restrict__ B,
    const float* __restrict__ bias, float* __restrict__ C) {
  __shared__ short lds[2][4][8192];  // [buf][A0,A1,B0,B1][16KB half]

  const int tid = threadIdx.x;
  const int wave = tid >> 6;
  const int lane = tid & 63;
  const int l15 = lane & 15;
  const int q4 = lane >> 4;
  const int wm = wave >> 2;  // 0..1
  const int wn = wave & 3;   // 0..3

  // XCD-chunked swizzle: 1280 blocks = 8 XCDs x 160; XCD g owns M-rows
  // [g*4, g*4+4) x tile-cols 0..39, walked 4-rows-fast.
  const int bid = blockIdx.x;
  const int g = bid & 7;
  const int idx = bid >> 3;  // 0..159
  const int brow = (g * 4 + (idx & 3)) * 256;
  const int bcol = (idx >> 2) * 256;  // cols 0..39

  // staging source (inverse-swizzled global addr; linear LDS dest)
  const int srow = tid >> 3;                             // 0..63
  const int scol = ((tid & 7) ^ ((tid >> 3) & 7)) << 3;  // element col
  const short* Asrc = A + (size_t)(brow + srow) * K_DIM + scol;
  const short* Bsrc = B + (size_t)(bcol + srow) * K_DIM + scol;
  const int wu0 = wave * 512;
  const int wu1 = 4096 + wave * 512;

  auto stageA = [&](int buf, int half, int t) {
    const short* s = Asrc + (size_t)half * 128 * K_DIM + t * 64;
    GLOAD(s, &lds[buf][half][wu0]);
    GLOAD(s + (size_t)64 * K_DIM, &lds[buf][half][wu1]);
  };
  auto stageB = [&](int buf, int half, int t) {
    const short* s = Bsrc + (size_t)half * 128 * K_DIM + t * 64;
    GLOAD(s, &lds[buf][2 + half][wu0]);
    GLOAD(s + (size_t)64 * K_DIM, &lds[buf][2 + half][wu1]);
  };

  // fragment read bases (swizzled): frag(m,kk) phys byte =
  //   (m*16+l15)*128 + (((kk<<2|q4) ^ (l15&7)) << 4)
  const int offk0 = ((q4 ^ (l15 & 7)) << 4);
  const int offk1 = offk0 ^ 64;
  const char* aP[2] = {(const char*)&lds[0][wm][0] + l15 * 128,
                       (const char*)&lds[1][wm][0] + l15 * 128};
  const char* bP[2] = {
      (const char*)&lds[0][2 + (wn >> 1)][0] + (wn & 1) * 8192 + l15 * 128,
      (const char*)&lds[1][2 + (wn >> 1)][0] + (wn & 1) * 8192 + l15 * 128};

  f32x4 acc[8][4] = {};
  bf16x8 afA[4], afB[4], bfA[4], bfB[4];

  // ---- prologue: stage buf0 (tile0, 4 halves) + B(1,0, tile1) ----
  stageB(0, 0, 0);
  stageB(0, 1, 0);
  stageA(0, 0, 0);
  stageA(0, 1, 0);
  stageB(1, 0, 1);
  asm volatile("s_waitcnt vmcnt(2)" ::: "memory");  // buf0's 8 loads landed
  __builtin_amdgcn_s_barrier();
#pragma unroll
  for (int m = 0; m < 4; ++m) afA[m] = *(const bf16x8*)(aP[0] + m * 2048 + offk0);
#pragma unroll
  for (int n = 0; n < 4; ++n) bfA[n] = *(const bf16x8*)(bP[0] + n * 2048 + offk0);

  for (int i = 0; i < 32; ++i) {
    const int t1 = 2 * i + 1;
    const int t2 = (2 * i + 2 < 64) ? 2 * i + 2 : 63;  // clamped tail (dead)
    const int t3 = (2 * i + 3 < 64) ? 2 * i + 3 : 63;

    // ph0: read S1 (buf0.A m4-7 kk0); stage B(1,1,t1); MFMA Q0
#pragma unroll
    for (int m = 0; m < 4; ++m)
      afB[m] = *(const bf16x8*)(aP[0] + (4 + m) * 2048 + offk0);
    stageB(1, 1, t1);
    WAIT_LGKM(4);
#pragma unroll
    for (int m = 0; m < 4; ++m)
#pragma unroll
      for (int n = 0; n < 4; ++n)
        acc[m][n] = __builtin_amdgcn_mfma_f32_16x16x32_bf16(afA[m], bfA[n],
                                                            acc[m][n], 0, 0, 0);
    ENDBAR();

    // ph1: read S2 (buf0.A m0-3 kk1 + buf0.B kk1); stage A(1,*,t1); Q1
#pragma unroll
    for (int m = 0; m < 4; ++m)
      afA[m] = *(const bf16x8*)(aP[0] + m * 2048 + offk1);
#pragma unroll
    for (int n = 0; n < 4; ++n)
      bfB[n] = *(const bf16x8*)(bP[0] + n * 2048 + offk1);
    stageA(1, 0, t1);
    stageA(1, 1, t1);
    WAIT_LGKM(8);
#pragma unroll
    for (int m = 0; m < 4; ++m)
#pragma unroll
      for (int n = 0; n < 4; ++n)
        acc[4 + m][n] = __builtin_amdgcn_mfma_f32_16x16x32_bf16(
            afB[m], bfA[n], acc[4 + m][n], 0, 0, 0);
    ENDBAR();

    // ph2: read S3 (buf0.A m4-7 kk1); Q2; END: vmcnt(0) [buf1 landed]
#pragma unroll
    for (int m = 0; m < 4; ++m)
      afB[m] = *(const bf16x8*)(aP[0] + (4 + m) * 2048 + offk1);
    WAIT_LGKM(4);
#pragma unroll
    for (int m = 0; m < 4; ++m)
#pragma unroll
      for (int n = 0; n < 4; ++n)
        acc[m][n] = __builtin_amdgcn_mfma_f32_16x16x32_bf16(afA[m], bfB[n],
                                                            acc[m][n], 0, 0, 0);
    ENDBAR_VM0();

    // ph3: read S4 (buf1.A m0-3 kk0 + buf1.B kk0); stage B(0,0,t2); Q3
#pragma unroll
    for (int m = 0; m < 4; ++m)
      afA[m] = *(const bf16x8*)(aP[1] + m * 2048 + offk0);
#pragma unroll
    for (int n = 0; n < 4; ++n)
      bfA[n] = *(const bf16x8*)(bP[1] + n * 2048 + offk0);
    stageB(0, 0, t2);
    WAIT_LGKM(8);
#pragma unroll
    for (int m = 0; m < 4; ++m)
#pragma unroll
      for (int n = 0; n < 4; ++n)
        acc[4 + m][n] = __builtin_amdgcn_mfma_f32_16x16x32_bf16(
            afB[m], bfB[n], acc[4 + m][n], 0, 0, 0);
    ENDBAR();

    // ph4: read S5 (buf1.A m4-7 kk0); stage B(0,1,t2); Q0'
#pragma unroll
    for (int m = 0; m < 4; ++m)
      afB[m] = *(const bf16x8*)(aP[1] + (4 + m) * 2048 + offk0);
    stageB(0, 1, t2);
    WAIT_LGKM(4);
#pragma unroll
    for (int m = 0; m < 4; ++m)
#pragma unroll
      for (int n = 0; n < 4; ++n)
        acc[m][n] = __builtin_amdgcn_mfma_f32_16x16x32_bf16(afA[m], bfA[n],
                                                            acc[m][n], 0, 0, 0);
    ENDBAR();

    // ph5: read S6 (buf1.A m0-3 kk1 + buf1.B kk1); stage A(0,*,t2); Q1'
#pragma unroll
    for (int m = 0; m < 4; ++m)
      afA[m] = *(const bf16x8*)(aP[1] + m * 2048 + offk1);
#pragma unroll
    for (int n = 0; n < 4; ++n)
      bfB[n] = *(const bf16x8*)(bP[1] + n * 2048 + offk1);
    stageA(0, 0, t2);
    stageA(0, 1, t2);
    WAIT_LGKM(8);
#pragma unroll
    for (int m = 0; m < 4; ++m)
#pragma unroll
      for (int n = 0; n < 4; ++n)
        acc[4 + m][n] = __builtin_amdgcn_mfma_f32_16x16x32_bf16(
            afB[m], bfA[n], acc[4 + m][n], 0, 0, 0);
    ENDBAR();

    // ph6: read S7 (buf1.A m4-7 kk1); Q2'; END: vmcnt(0) [buf0' landed]
#pragma unroll
    for (int m = 0; m < 4; ++m)
      afB[m] = *(const bf16x8*)(aP[1] + (4 + m) * 2048 + offk1);
    WAIT_LGKM(4);
#pragma unroll
    for (int m = 0; m < 4; ++m)
#pragma unroll
      for (int n = 0; n < 4; ++n)
        acc[m][n] = __builtin_amdgcn_mfma_f32_16x16x32_bf16(afA[m], bfB[n],
                                                            acc[m][n], 0, 0, 0);
    ENDBAR_VM0();

    // ph7: read S0' (buf0 NEW tile); stage B(1,0,t3); Q3'
#pragma unroll
    for (int m = 0; m < 4; ++m)
      afA[m] = *(const bf16x8*)(aP[0] + m * 2048 + offk0);
#pragma unroll
    for (int n = 0; n < 4; ++n)
      bfA[n] = *(const bf16x8*)(bP[0] + n * 2048 + offk0);
    stageB(1, 0, t3);
    WAIT_LGKM(8);
#pragma unroll
    for (int m = 0; m < 4; ++m)
#pragma unroll
      for (int n = 0; n < 4; ++n)
        acc[4 + m][n] = __builtin_amdgcn_mfma_f32_16x16x32_bf16(
            afB[m], bfB[n], acc[4 + m][n], 0, 0, 0);
    ENDBAR();
  }

  // ---- epilogue: C/D layout col=lane&15, row=(lane>>4)*4+j ----
  const int crow0 = brow + wm * 128 + q4 * 4;
  const int ccol0 = bcol + wn * 64 + l15;
#pragma unroll
  for (int n = 0; n < 4; ++n) {
    const float bv = bias[ccol0 + n * 16];
#pragma unroll
    for (int m = 0; m < 8; ++m) {
      const size_t rb = (size_t)(crow0 + m * 16) * N_DIM + (ccol0 + n * 16);
#pragma unroll
      for (int j = 0; j < 4; ++j) C[rb + (size_t)j * N_DIM] = acc[m][n][j] + bv;
    }
  }
}

// ---------------- Kernel 3: 128x128 m97 tail GEMM (N-cols 10240..11007) -----
// R2-proven structure (39% util, absmax 0.25). 384 blocks = 64 M-rows x 6
// N-cols of 128; small LDS (16KB) -> multi-resident, fills the tail round.
__global__ __launch_bounds__(256, 2) void gemm_bt_kernel(
    const short* __restrict__ A, const short* __restrict__ B,
    const float* __restrict__ bias, float* __restrict__ C) {
  __shared__ short Alds[128 * 32];
  __shared__ short Blds[128 * 32];

  const int tid = threadIdx.x;
  const int wave = tid >> 6;
  const int lane = tid & 63;
  const int wr = wave >> 1;
  const int wc = wave & 1;

  const int bid = blockIdx.x;  // 0..383
  const int brow = (bid & 63) * 128;
  const int bcol = (80 + (bid >> 6)) * 128;  // cols 10240..11007

  const int tr = tid >> 2;
  const int tc = (tid & 3) * 8;
  const short* Ag = A + (size_t)(brow + tr) * K_DIM + tc;
  const short* Bg = B + (size_t)(bcol + tr) * K_DIM + tc;

  short* AldsW = &Alds[wave * 512];
  short* BldsW = &Blds[wave * 512];

  f32x4 acc[4][4] = {};

  const int la = (lane & 15) * 32 + (lane >> 4) * 8;
  const short* Ar = &Alds[(wr * 64) * 32 + la];
  const short* Br = &Blds[(wc * 64) * 32 + la];

  for (int k0 = 0; k0 < K_DIM; k0 += 32) {
    GLOAD(Ag, AldsW);
    GLOAD(Ag + (size_t)64 * K_DIM, AldsW + 2048);
    GLOAD(Bg, BldsW);
    GLOAD(Bg + (size_t)64 * K_DIM, BldsW + 2048);
    __syncthreads();

    bf16x8 af[4], bfr[4];
#pragma unroll
    for (int m = 0; m < 4; ++m)
      af[m] = *reinterpret_cast<const bf16x8*>(Ar + m * 16 * 32);
#pragma unroll
    for (int n = 0; n < 4; ++n)
      bfr[n] = *reinterpret_cast<const bf16x8*>(Br + n * 16 * 32);

#pragma unroll
    for (int m = 0; m < 4; ++m)
#pragma unroll
      for (int n = 0; n < 4; ++n)
        acc[m][n] = __builtin_amdgcn_mfma_f32_16x16x32_bf16(af[m], bfr[n],
                                                            acc[m][n], 0, 0, 0);

    __syncthreads();
    Ag += 32;
    Bg += 32;
  }

  const int crow0 = brow + wr * 64 + (lane >> 4) * 4;
  const int ccol0 = bcol + wc * 64 + (lane & 15);
#pragma unroll
  for (int n = 0; n < 4; ++n) {
    const int cc = ccol0 + n * 16;
    const float bv = bias[cc];
#pragma unroll
    for (int m = 0; m < 4; ++m) {
      const size_t rbase = (size_t)(crow0 + m * 16) * N_DIM + cc;
#pragma unroll
      for (int j = 0; j < 4; ++j) C[rbase + (size_t)j * N_DIM] = acc[m][n][j] + bv;
    }
  }
}

extern "C" void kernel_launch(void* const* d_in, const int* in_sizes, int n_in,
                              void* d_out, int out_size, void* d_ws, size_t ws_size,
                              hipStream_t stream) {
  const float* x = (const float*)d_in[0];     // [8192, 4096]
  const float* w = (const float*)d_in[1];     // [11008, 4096]
  const float* bias = (const float*)d_in[2];  // [11008]
  float* out = (float*)d_out;                 // [8192, 11008]

  unsigned short* wq = (unsigned short*)d_ws;       // N*K bf16
  unsigned short* xb = wq + (size_t)N_DIM * K_DIM;  // M*K bf16

  prep_kernel<<<NQB + NCB, 256, 0, stream>>>(w, wq, x, (uint32_t*)xb);
  // main: tile-cols 0..39 (1280 blocks = 5 clean rounds, zero tail)
  gemm256_kernel<<<dim3(1280), 512, 0, stream>>>((const short*)xb,
                                                 (const short*)wq, bias, out);
  // tail: tile-cols 40..42 as 384 blocks of 128x128 (multi-resident)
  gemm_bt_kernel<<<dim3(384), 256, 0, stream>>>((const short*)xb,
                                                (const short*)wq, bias, out);
}